// Round 12
// baseline (97.614 us; speedup 1.0000x reference)
//
#include <hip/hip_runtime.h>
#include <math.h>

constexpr int B_ = 8192;
constexpr int T_ = 512;
constexpr int CH = 16;                     // steps per chunk / LDS tile
constexpr int NCH = T_ / CH;               // 32 chunks
constexpr int GRPS = B_ / 64;              // 128 session-groups
constexpr int ROWB = CH * 16 + 16;         // 272 B LDS row (pad) for chunk_logits flush
constexpr size_t PACK_BYTES = (size_t)B_ * T_;            // 4 MB
constexpr size_t SN = (size_t)GRPS * NCH * 64;            // 262144 snapshot entries
constexpr size_t SNAP_BYTES = SN * 3 * sizeof(float4);    // 12.6 MB (3 float4 planes)
constexpr size_t CS_BYTES = (size_t)7 * NCH * B_ * sizeof(float4);   // 29.4 MB (7 float4/chunk)

__device__ __forceinline__ float sp_(float x) {
    return fmaxf(x, 0.0f) + log1pf(expf(-fabsf(x)));  // stable softplus
}
__device__ __forceinline__ float sg_(float x) { return 1.0f / (1.0f + expf(-x)); }
__device__ __forceinline__ float clipf(float x, float lo, float hi) { return fminf(fmaxf(x, lo), hi); }
__device__ __forceinline__ float sel(bool c, float a, float b) { return c ? a : b; }

// carry state — all named scalars, statically indexed
struct CS { float q0, q1, q2, q3, c0, c1, c2, c3, tsls, expl; int oldc; };

// One carry step. Shared by all sequential paths -> bit-identical semantics.
__device__ __forceinline__ void step_carry(CS& s, unsigned int byte, float gamma, float decay,
                                           bool& same, bool& i0, bool& i1, bool& i2, bool& i3,
                                           int& cc_out) {
    const int  cc = (int)(byte & 3u);
    const bool rf = (byte & 4u) != 0u;
    const float target = sel(rf, 1.0f, -gamma);          // rv - gamma*(1-rv), rv in {0,1}
    same = (cc == s.oldc);
    s.tsls = sel(same, s.tsls + 1.0f, 0.0f);
    s.expl *= (1.0f - 1e-3f);
    i0 = (cc == 0); i1 = (cc == 1); i2 = (cc == 2); i3 = (cc == 3);
    s.q0 = sel(i0, target, s.q0);  s.c0 += sel(i0, 1.0f, 0.0f);
    s.q1 = sel(i1, target, s.q1);  s.c1 += sel(i1, 1.0f, 0.0f);
    s.q2 = sel(i2, target, s.q2);  s.c2 += sel(i2, 1.0f, 0.0f);
    s.q3 = sel(i3, target, s.q3);  s.c3 += sel(i3, 1.0f, 0.0f);
    const float qm  = 0.25f * ((s.q0 + s.q1) + (s.q2 + s.q3));
    const float omd = (1.0f - s.expl) * decay;
    const float eqd = (s.expl * decay) * qm;
    s.q0 = fmaf(omd, s.q0, eqd);
    s.q1 = fmaf(omd, s.q1, eqd);
    s.q2 = fmaf(omd, s.q2, eqd);
    s.q3 = fmaf(omd, s.q3, eqd);
    s.oldc = cc;
    cc_out = cc;
}

// ================= PRIMARY PATH =================

// ---- pass 1: thread-per-step pack (the R5 shape — measured fast ~27 µs). One float4
// load + one same-line scalar per thread, 2M threads, no inter-instruction deps. ----
__global__ __launch_bounds__(256) void pack_kernel(const float* __restrict__ in,
                                                   unsigned char* __restrict__ pk) {
    const int tid  = blockIdx.x * 256 + threadIdx.x;      // 0 .. B*T-1
    const int ti   = tid & 15;
    const int lane = (tid >> 4) & 63;
    const int tile = (tid >> 10) & (NCH - 1);
    const int grp  = tid >> 15;
    const int b = (grp << 6) | lane;
    const int t = (tile << 4) | ti;
    const float* base = in + ((size_t)b * T_ + t) * 8;
    const float4 a = *reinterpret_cast<const float4*>(base);
    const float  r = base[4];
    const int cc = a.y > 0.5f ? 1 : (a.z > 0.5f ? 2 : (a.w > 0.5f ? 3 : 0));
    pk[tid] = (unsigned char)(cc | ((r > 0.5f) ? 4 : 0));
}

// ---- pass 2: per-chunk affine summary from packed codes (VALU-bound, high occupancy) ----
__global__ __launch_bounds__(256) void chunk_affine2(const unsigned char* __restrict__ pk,
                                                     const float* __restrict__ p,
                                                     float4* __restrict__ cs4) {
    const int t    = blockIdx.x * 256 + threadIdx.x;   // 0 .. B*NCH-1
    const int bid  = t >> 6;             // grp*NCH + k
    const int lane = t & 63;
    const int k    = bid & (NCH - 1);
    const int grp  = bid >> 5;
    const int b    = grp * 64 + lane;

    const float alpha = clipf(sg_(p[3]), 0.01f, 0.99f);
    const float decay = clipf(sg_(p[4]), 0.01f, 0.99f);
    const float gamma = sp_(p[10]);

    // expl at chunk start: alpha * 0.999^(16k)  (~1e-7 rel err vs serial chain; harmless)
    float e = alpha * __powf(1.0f - 1e-3f, (float)(CH * k));

    const uint4 cur = reinterpret_cast<const uint4*>(pk)[(size_t)bid * 64 + lane];

    float m[4][4], v[4], n[4];
#pragma unroll
    for (int i = 0; i < 4; ++i) {
#pragma unroll
        for (int j = 0; j < 4; ++j) m[i][j] = (i == j) ? 1.0f : 0.0f;
        v[i] = 0.0f; n[i] = 0.0f;
    }
    int prev = -1, run = 0;

#pragma unroll
    for (int ti = 0; ti < CH; ++ti) {
        const unsigned word = (ti < 4) ? cur.x : (ti < 8) ? cur.y : (ti < 12) ? cur.z : cur.w;
        const unsigned byte = (word >> (8 * (ti & 3))) & 0xffu;
        const int  cc = (int)(byte & 3u);
        const bool rf = (byte & 4u) != 0u;
        const float tgt = rf ? 1.0f : -gamma;
        e *= (1.0f - 1e-3f);
        run = (cc == prev) ? (run + 1) : 1;
        prev = cc;
        // P: zero row cc of M, overwrite v[cc] = tgt; count action
#pragma unroll
        for (int i = 0; i < 4; ++i) {
            const bool hit = (i == cc);
            v[i] = hit ? tgt : v[i];
            n[i] += hit ? 1.0f : 0.0f;
#pragma unroll
            for (int j = 0; j < 4; ++j) m[i][j] = hit ? 0.0f : m[i][j];
        }
        // S = decay * [(1-e) I + (e/4) J]
        const float aa = decay * (1.0f - e);
        const float bf = decay * e * 0.25f;
        float csum[4];
#pragma unroll
        for (int j = 0; j < 4; ++j) csum[j] = bf * ((m[0][j] + m[1][j]) + (m[2][j] + m[3][j]));
        const float vs = bf * ((v[0] + v[1]) + (v[2] + v[3]));
#pragma unroll
        for (int i = 0; i < 4; ++i) {
#pragma unroll
            for (int j = 0; j < 4; ++j) m[i][j] = fmaf(aa, m[i][j], csum[j]);
            v[i] = fmaf(aa, v[i], vs);
        }
    }

    // cs: 7 float4 planes per chunk: M rows 0-3, v, n, (lc, run, 0, 0) — coalesced
    cs4[((size_t)k * 7 + 0) * B_ + b] = make_float4(m[0][0], m[0][1], m[0][2], m[0][3]);
    cs4[((size_t)k * 7 + 1) * B_ + b] = make_float4(m[1][0], m[1][1], m[1][2], m[1][3]);
    cs4[((size_t)k * 7 + 2) * B_ + b] = make_float4(m[2][0], m[2][1], m[2][2], m[2][3]);
    cs4[((size_t)k * 7 + 3) * B_ + b] = make_float4(m[3][0], m[3][1], m[3][2], m[3][3]);
    cs4[((size_t)k * 7 + 4) * B_ + b] = make_float4(v[0], v[1], v[2], v[3]);
    cs4[((size_t)k * 7 + 5) * B_ + b] = make_float4(n[0], n[1], n[2], n[3]);
    cs4[((size_t)k * 7 + 6) * B_ + b] = make_float4((float)prev, (float)run, 0.0f, 0.0f);
}

// ---- pass 3: boundary prefix, 128 blocks x 64 thr, float4 loads, depth-2 pipeline ----
__global__ __launch_bounds__(64, 1) void boundary_prefix3(const float4* __restrict__ cs4,
                                                          const float* __restrict__ p,
                                                          float4* __restrict__ snap4) {
    const int b   = blockIdx.x * 64 + threadIdx.x;   // session
    const int grp = b >> 6;
    const int l   = b & 63;

    const float prior = clipf(sp_(p[2]), 0.01f, 0.99f);
    const float alpha = clipf(sg_(p[3]), 0.01f, 0.99f);

    float q[4], c[4];
#pragma unroll
    for (int i = 0; i < 4; ++i) { q[i] = prior; c[i] = 0.0f; }
    float e = alpha;
    float ER = 0.0f;
    float lcprev = -1.0f;
    float tsls = 0.0f;

    float4 buf[3][7];   // depth-2 pipeline; static indices under full unroll
#pragma unroll
    for (int j = 0; j < 7; ++j) buf[0][j] = cs4[((size_t)0 * 7 + j) * B_ + b];
#pragma unroll
    for (int j = 0; j < 7; ++j) buf[1][j] = cs4[((size_t)1 * 7 + j) * B_ + b];

#pragma unroll
    for (int k = 0; k < NCH; ++k) {
        if (k + 2 < NCH) {
#pragma unroll
            for (int j = 0; j < 7; ++j)
                buf[(k + 2) % 3][j] = cs4[((size_t)(k + 2) * 7 + j) * B_ + b];
        }

        // snapshot = state BEFORE chunk k (exact sequential e chain preserved)
        const size_t sb = (size_t)(grp * NCH + k) * 64 + l;
        snap4[0 * SN + sb] = make_float4(q[0], q[1], q[2], q[3]);
        snap4[1 * SN + sb] = make_float4(c[0], c[1], c[2], c[3]);
        snap4[2 * SN + sb] = make_float4(tsls, e, lcprev, 0.0f);

        // q <- M q + v ; c += n
        const float4 m0 = buf[k % 3][0], m1 = buf[k % 3][1];
        const float4 m2 = buf[k % 3][2], m3 = buf[k % 3][3];
        const float4 vv = buf[k % 3][4], nn = buf[k % 3][5];
        const float4 mt = buf[k % 3][6];
        float nq0 = fmaf(m0.x, q[0], fmaf(m0.y, q[1], fmaf(m0.z, q[2], fmaf(m0.w, q[3], vv.x))));
        float nq1 = fmaf(m1.x, q[0], fmaf(m1.y, q[1], fmaf(m1.z, q[2], fmaf(m1.w, q[3], vv.y))));
        float nq2 = fmaf(m2.x, q[0], fmaf(m2.y, q[1], fmaf(m2.z, q[2], fmaf(m2.w, q[3], vv.z))));
        float nq3 = fmaf(m3.x, q[0], fmaf(m3.y, q[1], fmaf(m3.z, q[2], fmaf(m3.w, q[3], vv.w))));
        q[0] = nq0; q[1] = nq1; q[2] = nq2; q[3] = nq3;
        c[0] += nn.x; c[1] += nn.y; c[2] += nn.z; c[3] += nn.w;

        const float lc = mt.x, run = mt.y;
        ER = (run == 16.0f && lc == lcprev) ? (ER + 16.0f) : run;
        tsls = ER - 1.0f;
        lcprev = lc;

#pragma unroll
        for (int i = 0; i < CH; ++i) e *= (1.0f - 1e-3f);
    }
}

// ---- pass 4: per-chunk logits, float4 snap loads (unchanged, proven) ----
__global__ __launch_bounds__(64) void chunk_logits(const unsigned char* __restrict__ pk,
                                                   const float* __restrict__ p,
                                                   const float4* __restrict__ snap4,
                                                   float* __restrict__ out) {
    __shared__ unsigned char lds[64 * ROWB];
    const int l   = threadIdx.x;
    const int bid = blockIdx.x;          // = grp*NCH + k
    const int k   = bid & (NCH - 1);
    const int grp = bid >> 5;            // NCH == 32

    const float beta_r = clipf(sp_(p[0]), 0.01f, 20.0f);
    const float lapse  = clipf(sg_(p[1]), 0.01f, 0.99f);
    const float decay  = clipf(sg_(p[4]), 0.01f, 0.99f);
    const float ab1    = p[5];
    const float ab2    = p[6];
    const float pers   = sp_(p[7]);
    const float sw     = p[8];
    const float gamma  = sp_(p[10]);
    const float temp   = clipf(sp_(p[11]) + 1e-6f, 1e-6f, 100.0f);
    const float beta_p = sp_(p[12]);
    const float brt = beta_r / temp;
    const float l4  = lapse * 0.25f;
    const float oml = 1.0f - lapse;

    const size_t sb = (size_t)bid * 64 + l;
    const float4 qv = snap4[0 * SN + sb];
    const float4 cv = snap4[1 * SN + sb];
    const float4 mv = snap4[2 * SN + sb];
    CS s;
    s.q0 = qv.x; s.q1 = qv.y; s.q2 = qv.z; s.q3 = qv.w;
    s.c0 = cv.x; s.c1 = cv.y; s.c2 = cv.z; s.c3 = cv.w;
    s.tsls = mv.x; s.expl = mv.y; s.oldc = (int)mv.z;

    const uint4 cur = reinterpret_cast<const uint4*>(pk)[(size_t)bid * 64 + l];

#pragma unroll
    for (int ti = 0; ti < CH; ++ti) {
        const unsigned int word = (ti < 4) ? cur.x : (ti < 8) ? cur.y : (ti < 12) ? cur.z : cur.w;
        const unsigned int byte = (word >> (8 * (ti & 3))) & 0xffu;
        const int prev = s.oldc;
        bool same, i0, i1, i2, i3; int cc;
        step_carry(s, byte, gamma, decay, same, i0, i1, i2, i3, cc);

        const float s0 = fmaf(brt, s.q0, beta_p * __logf(1.0f + s.c0));
        const float s1 = fmaf(brt, s.q1, beta_p * __logf(1.0f + s.c1));
        const float s2 = fmaf(brt, s.q2, beta_p * __logf(1.0f + s.c2));
        const float s3 = fmaf(brt, s.q3, beta_p * __logf(1.0f + s.c3));
        const float m  = fmaxf(fmaxf(s0, s1), fmaxf(s2, s3));
        const float e0 = __expf(s0 - m);
        const float e1 = __expf(s1 - m);
        const float e2 = __expf(s2 - m);
        const float e3 = __expf(s3 - m);
        const float iz = oml / ((e0 + e1) + (e2 + e3));

        float l0 = __logf(fmaf(e0, iz, l4));
        float l1 = __logf(fmaf(e1, iz, l4));
        float l2 = __logf(fmaf(e2, iz, l4));
        float l3 = __logf(fmaf(e3, iz, l4));

        const float bcc = sel(same, pers, sw) + __logf(s.tsls + 1.0f);
        const int cc2 = cc ^ 2;
        l0 += sel(i0, bcc, 0.0f) + sel(prev == 0, ab1, 0.0f) + sel(cc2 == 0, ab2, 0.0f);
        l1 += sel(i1, bcc, 0.0f) + sel(prev == 1, ab1, 0.0f) + sel(cc2 == 1, ab2, 0.0f);
        l2 += sel(i2, bcc, 0.0f) + sel(prev == 2, ab1, 0.0f) + sel(cc2 == 2, ab2, 0.0f);
        l3 += sel(i3, bcc, 0.0f) + sel(prev == 3, ab1, 0.0f) + sel(cc2 == 3, ab2, 0.0f);

        *reinterpret_cast<float4*>(&lds[l * ROWB + ti * 16]) = make_float4(l0, l1, l2, l3);
    }

    __syncthreads();
    float4* __restrict__ out4 = reinterpret_cast<float4*>(out);
#pragma unroll
    for (int pp = 0; pp < 16; ++pp) {
        const int ss = pp * 4 + (l >> 4);    // session within group
        const int st = l & 15;               // step within chunk
        const float4 v = *reinterpret_cast<const float4*>(&lds[ss * ROWB + st * 16]);
        out4[((size_t)(grp * 64 + ss)) * T_ + k * CH + st] = v;   // coalesced wave-store
    }
}

// ================= FALLBACK (small ws): pack + monolithic packed scan =================

__global__ __launch_bounds__(64, 1) void castro_scan_packed(
    const unsigned char* __restrict__ pk, const float* __restrict__ p, float* __restrict__ out)
{
    __shared__ unsigned char lds[64 * ROWB];
    const int l = threadIdx.x, blk = blockIdx.x;
    const float beta_r = clipf(sp_(p[0]), 0.01f, 20.0f);
    const float lapse  = clipf(sg_(p[1]), 0.01f, 0.99f);
    const float prior  = clipf(sp_(p[2]), 0.01f, 0.99f);
    const float alpha  = clipf(sg_(p[3]), 0.01f, 0.99f);
    const float decay  = clipf(sg_(p[4]), 0.01f, 0.99f);
    const float ab1 = p[5], ab2 = p[6];
    const float pers = sp_(p[7]), sw = p[8];
    const float gamma = sp_(p[10]);
    const float temp = clipf(sp_(p[11]) + 1e-6f, 1e-6f, 100.0f);
    const float beta_p = sp_(p[12]);
    const float brt = beta_r / temp, l4 = lapse * 0.25f, oml = 1.0f - lapse;
    CS s; s.q0 = s.q1 = s.q2 = s.q3 = prior;
    s.c0 = s.c1 = s.c2 = s.c3 = 0.0f; s.tsls = 0.0f; s.expl = alpha; s.oldc = -1;
    const uint4* pkt = reinterpret_cast<const uint4*>(pk + (size_t)blk * (NCH * 1024)) + l;
    float4* out4 = reinterpret_cast<float4*>(out);
    uint4 cur = pkt[0];
    for (int k = 0; k < NCH; ++k) {
        const uint4 nxt = pkt[(k + 1 < NCH ? k + 1 : k) * 64];
#pragma unroll
        for (int ti = 0; ti < CH; ++ti) {
            const unsigned int word = (ti < 4) ? cur.x : (ti < 8) ? cur.y : (ti < 12) ? cur.z : cur.w;
            const unsigned int byte = (word >> (8 * (ti & 3))) & 0xffu;
            const int prev = s.oldc;
            bool same, i0, i1, i2, i3; int cc;
            step_carry(s, byte, gamma, decay, same, i0, i1, i2, i3, cc);
            const float s0 = fmaf(brt, s.q0, beta_p * __logf(1.0f + s.c0));
            const float s1 = fmaf(brt, s.q1, beta_p * __logf(1.0f + s.c1));
            const float s2 = fmaf(brt, s.q2, beta_p * __logf(1.0f + s.c2));
            const float s3 = fmaf(brt, s.q3, beta_p * __logf(1.0f + s.c3));
            const float m = fmaxf(fmaxf(s0, s1), fmaxf(s2, s3));
            const float e0 = __expf(s0 - m), e1 = __expf(s1 - m);
            const float e2 = __expf(s2 - m), e3 = __expf(s3 - m);
            const float iz = oml / ((e0 + e1) + (e2 + e3));
            float l0 = __logf(fmaf(e0, iz, l4)), l1 = __logf(fmaf(e1, iz, l4));
            float l2 = __logf(fmaf(e2, iz, l4)), l3 = __logf(fmaf(e3, iz, l4));
            const float bcc = sel(same, pers, sw) + __logf(s.tsls + 1.0f);
            const int cc2 = cc ^ 2;
            l0 += sel(i0, bcc, 0.f) + sel(prev == 0, ab1, 0.f) + sel(cc2 == 0, ab2, 0.f);
            l1 += sel(i1, bcc, 0.f) + sel(prev == 1, ab1, 0.f) + sel(cc2 == 1, ab2, 0.f);
            l2 += sel(i2, bcc, 0.f) + sel(prev == 2, ab1, 0.f) + sel(cc2 == 2, ab2, 0.f);
            l3 += sel(i3, bcc, 0.f) + sel(prev == 3, ab1, 0.f) + sel(cc2 == 3, ab2, 0.f);
            *reinterpret_cast<float4*>(&lds[l * ROWB + ti * 16]) = make_float4(l0, l1, l2, l3);
        }
        __syncthreads();
#pragma unroll
        for (int pp = 0; pp < 16; ++pp) {
            const int ss = pp * 4 + (l >> 4);
            const int st = l & 15;
            const float4 v = *reinterpret_cast<const float4*>(&lds[ss * ROWB + st * 16]);
            out4[((size_t)(blk * 64 + ss)) * T_ + k * CH + st] = v;
        }
        __syncthreads();
        cur = nxt;
    }
}

extern "C" void kernel_launch(void* const* d_in, const int* in_sizes, int n_in,
                              void* d_out, int out_size, void* d_ws, size_t ws_size,
                              hipStream_t stream) {
    const float* inputs = (const float*)d_in[0];   // [8192, 512, 8] f32
    const float* params = (const float*)d_in[1];   // [13] f32
    float* out = (float*)d_out;                    // [8192, 512, 4] f32

    if (ws_size >= PACK_BYTES + SNAP_BYTES + CS_BYTES) {
        unsigned char* pk = (unsigned char*)d_ws;
        float4* snap4 = (float4*)((char*)d_ws + PACK_BYTES);
        float4* cs4   = (float4*)((char*)d_ws + PACK_BYTES + SNAP_BYTES);
        pack_kernel<<<dim3((B_ * T_) / 256), dim3(256), 0, stream>>>(inputs, pk);
        chunk_affine2<<<dim3(B_ * NCH / 256), dim3(256), 0, stream>>>(pk, params, cs4);
        boundary_prefix3<<<dim3(B_ / 64), dim3(64), 0, stream>>>(cs4, params, snap4);
        chunk_logits<<<dim3(GRPS * NCH), dim3(64), 0, stream>>>(pk, params, snap4, out);
    } else if (ws_size >= PACK_BYTES) {
        unsigned char* pk = (unsigned char*)d_ws;
        pack_kernel<<<dim3((B_ * T_) / 256), dim3(256), 0, stream>>>(inputs, pk);
        castro_scan_packed<<<dim3(GRPS), dim3(64), 0, stream>>>(pk, params, out);
    }
}

// Round 13
// 97.370 us; speedup vs baseline: 1.0025x; 1.0025x over previous
//
#include <hip/hip_runtime.h>
#include <math.h>

constexpr int B_ = 8192;
constexpr int T_ = 512;
constexpr int CH = 16;                     // steps per chunk / LDS tile
constexpr int NCH = T_ / CH;               // 32 chunks
constexpr int GRPS = B_ / 64;              // 128 session-groups
constexpr int ROWB = CH * 16 + 16;         // 272 B LDS row (pad) for chunk_logits flush
constexpr size_t PACK_BYTES = (size_t)B_ * T_;            // 4 MB
constexpr size_t SN = (size_t)GRPS * NCH * 64;            // 262144 snapshot entries
constexpr size_t SNAP_BYTES = SN * 3 * sizeof(float4);    // 12.6 MB (3 float4 planes)
constexpr size_t CS_BYTES = (size_t)7 * NCH * B_ * sizeof(float4);   // 29.4 MB (7 float4/chunk)

__device__ __forceinline__ float sp_(float x) {
    return fmaxf(x, 0.0f) + log1pf(expf(-fabsf(x)));  // stable softplus
}
__device__ __forceinline__ float sg_(float x) { return 1.0f / (1.0f + expf(-x)); }
__device__ __forceinline__ float clipf(float x, float lo, float hi) { return fminf(fmaxf(x, lo), hi); }
__device__ __forceinline__ float sel(bool c, float a, float b) { return c ? a : b; }

// carry state — all named scalars, statically indexed
struct CS { float q0, q1, q2, q3, c0, c1, c2, c3, tsls, expl; int oldc; };

// One carry step. Shared by all sequential paths -> bit-identical semantics.
__device__ __forceinline__ void step_carry(CS& s, unsigned int byte, float gamma, float decay,
                                           bool& same, bool& i0, bool& i1, bool& i2, bool& i3,
                                           int& cc_out) {
    const int  cc = (int)(byte & 3u);
    const bool rf = (byte & 4u) != 0u;
    const float target = sel(rf, 1.0f, -gamma);          // rv - gamma*(1-rv), rv in {0,1}
    same = (cc == s.oldc);
    s.tsls = sel(same, s.tsls + 1.0f, 0.0f);
    s.expl *= (1.0f - 1e-3f);
    i0 = (cc == 0); i1 = (cc == 1); i2 = (cc == 2); i3 = (cc == 3);
    s.q0 = sel(i0, target, s.q0);  s.c0 += sel(i0, 1.0f, 0.0f);
    s.q1 = sel(i1, target, s.q1);  s.c1 += sel(i1, 1.0f, 0.0f);
    s.q2 = sel(i2, target, s.q2);  s.c2 += sel(i2, 1.0f, 0.0f);
    s.q3 = sel(i3, target, s.q3);  s.c3 += sel(i3, 1.0f, 0.0f);
    const float qm  = 0.25f * ((s.q0 + s.q1) + (s.q2 + s.q3));
    const float omd = (1.0f - s.expl) * decay;
    const float eqd = (s.expl * decay) * qm;
    s.q0 = fmaf(omd, s.q0, eqd);
    s.q1 = fmaf(omd, s.q1, eqd);
    s.q2 = fmaf(omd, s.q2, eqd);
    s.q3 = fmaf(omd, s.q3, eqd);
    s.oldc = cc;
    cc_out = cc;
}

// ================= PRIMARY PATH =================

// ---- pass 1: thread-per-step pack (R5 shape, measured ~28 µs) ----
__global__ __launch_bounds__(256) void pack_kernel(const float* __restrict__ in,
                                                   unsigned char* __restrict__ pk) {
    const int tid  = blockIdx.x * 256 + threadIdx.x;      // 0 .. B*T-1
    const int ti   = tid & 15;
    const int lane = (tid >> 4) & 63;
    const int tile = (tid >> 10) & (NCH - 1);
    const int grp  = tid >> 15;
    const int b = (grp << 6) | lane;
    const int t = (tile << 4) | ti;
    const float* base = in + ((size_t)b * T_ + t) * 8;
    const float4 a = *reinterpret_cast<const float4*>(base);
    const float  r = base[4];
    const int cc = a.y > 0.5f ? 1 : (a.z > 0.5f ? 2 : (a.w > 0.5f ? 3 : 0));
    pk[tid] = (unsigned char)(cc | ((r > 0.5f) ? 4 : 0));
}

// ---- pass 2: per-chunk affine summary. __launch_bounds__(256,4): VGPR cap 128 so the
// m[4][4]+v+n working set (~55 live regs) stays in registers — the plain (256) build
// compiled to 36 VGPRs (R9 counter), spilling the matrix to scratch every step. ----
__global__ __launch_bounds__(256, 4) void chunk_affine2(const unsigned char* __restrict__ pk,
                                                        const float* __restrict__ p,
                                                        float4* __restrict__ cs4) {
    const int t    = blockIdx.x * 256 + threadIdx.x;   // 0 .. B*NCH-1
    const int bid  = t >> 6;             // grp*NCH + k
    const int lane = t & 63;
    const int k    = bid & (NCH - 1);
    const int grp  = bid >> 5;
    const int b    = grp * 64 + lane;

    const float alpha = clipf(sg_(p[3]), 0.01f, 0.99f);
    const float decay = clipf(sg_(p[4]), 0.01f, 0.99f);
    const float gamma = sp_(p[10]);

    // expl at chunk start: alpha * 0.999^(16k)  (~1e-7 rel err vs serial chain; harmless)
    float e = alpha * __powf(1.0f - 1e-3f, (float)(CH * k));

    const uint4 cur = reinterpret_cast<const uint4*>(pk)[(size_t)bid * 64 + lane];

    float m[4][4], v[4], n[4];
#pragma unroll
    for (int i = 0; i < 4; ++i) {
#pragma unroll
        for (int j = 0; j < 4; ++j) m[i][j] = (i == j) ? 1.0f : 0.0f;
        v[i] = 0.0f; n[i] = 0.0f;
    }
    int prev = -1, run = 0;

#pragma unroll
    for (int ti = 0; ti < CH; ++ti) {
        const unsigned word = (ti < 4) ? cur.x : (ti < 8) ? cur.y : (ti < 12) ? cur.z : cur.w;
        const unsigned byte = (word >> (8 * (ti & 3))) & 0xffu;
        const int  cc = (int)(byte & 3u);
        const bool rf = (byte & 4u) != 0u;
        const float tgt = rf ? 1.0f : -gamma;
        e *= (1.0f - 1e-3f);
        run = (cc == prev) ? (run + 1) : 1;
        prev = cc;
        // P: zero row cc of M, overwrite v[cc] = tgt; count action
#pragma unroll
        for (int i = 0; i < 4; ++i) {
            const bool hit = (i == cc);
            v[i] = hit ? tgt : v[i];
            n[i] += hit ? 1.0f : 0.0f;
#pragma unroll
            for (int j = 0; j < 4; ++j) m[i][j] = hit ? 0.0f : m[i][j];
        }
        // S = decay * [(1-e) I + (e/4) J]
        const float aa = decay * (1.0f - e);
        const float bf = decay * e * 0.25f;
        float csum[4];
#pragma unroll
        for (int j = 0; j < 4; ++j) csum[j] = bf * ((m[0][j] + m[1][j]) + (m[2][j] + m[3][j]));
        const float vs = bf * ((v[0] + v[1]) + (v[2] + v[3]));
#pragma unroll
        for (int i = 0; i < 4; ++i) {
#pragma unroll
            for (int j = 0; j < 4; ++j) m[i][j] = fmaf(aa, m[i][j], csum[j]);
            v[i] = fmaf(aa, v[i], vs);
        }
    }

    // cs: 7 float4 planes per chunk: M rows 0-3, v, n, (lc, run, 0, 0) — coalesced
    cs4[((size_t)k * 7 + 0) * B_ + b] = make_float4(m[0][0], m[0][1], m[0][2], m[0][3]);
    cs4[((size_t)k * 7 + 1) * B_ + b] = make_float4(m[1][0], m[1][1], m[1][2], m[1][3]);
    cs4[((size_t)k * 7 + 2) * B_ + b] = make_float4(m[2][0], m[2][1], m[2][2], m[2][3]);
    cs4[((size_t)k * 7 + 3) * B_ + b] = make_float4(m[3][0], m[3][1], m[3][2], m[3][3]);
    cs4[((size_t)k * 7 + 4) * B_ + b] = make_float4(v[0], v[1], v[2], v[3]);
    cs4[((size_t)k * 7 + 5) * B_ + b] = make_float4(n[0], n[1], n[2], n[3]);
    cs4[((size_t)k * 7 + 6) * B_ + b] = make_float4((float)prev, (float)run, 0.0f, 0.0f);
}

// ---- pass 3: boundary prefix, 128 blocks x 64 thr, float4 loads, depth-2 pipeline ----
__global__ __launch_bounds__(64, 1) void boundary_prefix3(const float4* __restrict__ cs4,
                                                          const float* __restrict__ p,
                                                          float4* __restrict__ snap4) {
    const int b   = blockIdx.x * 64 + threadIdx.x;   // session
    const int grp = b >> 6;
    const int l   = b & 63;

    const float prior = clipf(sp_(p[2]), 0.01f, 0.99f);
    const float alpha = clipf(sg_(p[3]), 0.01f, 0.99f);

    float q[4], c[4];
#pragma unroll
    for (int i = 0; i < 4; ++i) { q[i] = prior; c[i] = 0.0f; }
    float e = alpha;
    float ER = 0.0f;
    float lcprev = -1.0f;
    float tsls = 0.0f;

    float4 buf[3][7];   // depth-2 pipeline; static indices under full unroll
#pragma unroll
    for (int j = 0; j < 7; ++j) buf[0][j] = cs4[((size_t)0 * 7 + j) * B_ + b];
#pragma unroll
    for (int j = 0; j < 7; ++j) buf[1][j] = cs4[((size_t)1 * 7 + j) * B_ + b];

#pragma unroll
    for (int k = 0; k < NCH; ++k) {
        if (k + 2 < NCH) {
#pragma unroll
            for (int j = 0; j < 7; ++j)
                buf[(k + 2) % 3][j] = cs4[((size_t)(k + 2) * 7 + j) * B_ + b];
        }

        // snapshot = state BEFORE chunk k (exact sequential e chain preserved)
        const size_t sb = (size_t)(grp * NCH + k) * 64 + l;
        snap4[0 * SN + sb] = make_float4(q[0], q[1], q[2], q[3]);
        snap4[1 * SN + sb] = make_float4(c[0], c[1], c[2], c[3]);
        snap4[2 * SN + sb] = make_float4(tsls, e, lcprev, 0.0f);

        // q <- M q + v ; c += n
        const float4 m0 = buf[k % 3][0], m1 = buf[k % 3][1];
        const float4 m2 = buf[k % 3][2], m3 = buf[k % 3][3];
        const float4 vv = buf[k % 3][4], nn = buf[k % 3][5];
        const float4 mt = buf[k % 3][6];
        float nq0 = fmaf(m0.x, q[0], fmaf(m0.y, q[1], fmaf(m0.z, q[2], fmaf(m0.w, q[3], vv.x))));
        float nq1 = fmaf(m1.x, q[0], fmaf(m1.y, q[1], fmaf(m1.z, q[2], fmaf(m1.w, q[3], vv.y))));
        float nq2 = fmaf(m2.x, q[0], fmaf(m2.y, q[1], fmaf(m2.z, q[2], fmaf(m2.w, q[3], vv.z))));
        float nq3 = fmaf(m3.x, q[0], fmaf(m3.y, q[1], fmaf(m3.z, q[2], fmaf(m3.w, q[3], vv.w))));
        q[0] = nq0; q[1] = nq1; q[2] = nq2; q[3] = nq3;
        c[0] += nn.x; c[1] += nn.y; c[2] += nn.z; c[3] += nn.w;

        const float lc = mt.x, run = mt.y;
        ER = (run == 16.0f && lc == lcprev) ? (ER + 16.0f) : run;
        tsls = ER - 1.0f;
        lcprev = lc;

#pragma unroll
        for (int i = 0; i < CH; ++i) e *= (1.0f - 1e-3f);
    }
}

// ---- pass 4: per-chunk logits, float4 snap loads (unchanged, proven) ----
__global__ __launch_bounds__(64) void chunk_logits(const unsigned char* __restrict__ pk,
                                                   const float* __restrict__ p,
                                                   const float4* __restrict__ snap4,
                                                   float* __restrict__ out) {
    __shared__ unsigned char lds[64 * ROWB];
    const int l   = threadIdx.x;
    const int bid = blockIdx.x;          // = grp*NCH + k
    const int k   = bid & (NCH - 1);
    const int grp = bid >> 5;            // NCH == 32

    const float beta_r = clipf(sp_(p[0]), 0.01f, 20.0f);
    const float lapse  = clipf(sg_(p[1]), 0.01f, 0.99f);
    const float decay  = clipf(sg_(p[4]), 0.01f, 0.99f);
    const float ab1    = p[5];
    const float ab2    = p[6];
    const float pers   = sp_(p[7]);
    const float sw     = p[8];
    const float gamma  = sp_(p[10]);
    const float temp   = clipf(sp_(p[11]) + 1e-6f, 1e-6f, 100.0f);
    const float beta_p = sp_(p[12]);
    const float brt = beta_r / temp;
    const float l4  = lapse * 0.25f;
    const float oml = 1.0f - lapse;

    const size_t sb = (size_t)bid * 64 + l;
    const float4 qv = snap4[0 * SN + sb];
    const float4 cv = snap4[1 * SN + sb];
    const float4 mv = snap4[2 * SN + sb];
    CS s;
    s.q0 = qv.x; s.q1 = qv.y; s.q2 = qv.z; s.q3 = qv.w;
    s.c0 = cv.x; s.c1 = cv.y; s.c2 = cv.z; s.c3 = cv.w;
    s.tsls = mv.x; s.expl = mv.y; s.oldc = (int)mv.z;

    const uint4 cur = reinterpret_cast<const uint4*>(pk)[(size_t)bid * 64 + l];

#pragma unroll
    for (int ti = 0; ti < CH; ++ti) {
        const unsigned int word = (ti < 4) ? cur.x : (ti < 8) ? cur.y : (ti < 12) ? cur.z : cur.w;
        const unsigned int byte = (word >> (8 * (ti & 3))) & 0xffu;
        const int prev = s.oldc;
        bool same, i0, i1, i2, i3; int cc;
        step_carry(s, byte, gamma, decay, same, i0, i1, i2, i3, cc);

        const float s0 = fmaf(brt, s.q0, beta_p * __logf(1.0f + s.c0));
        const float s1 = fmaf(brt, s.q1, beta_p * __logf(1.0f + s.c1));
        const float s2 = fmaf(brt, s.q2, beta_p * __logf(1.0f + s.c2));
        const float s3 = fmaf(brt, s.q3, beta_p * __logf(1.0f + s.c3));
        const float m  = fmaxf(fmaxf(s0, s1), fmaxf(s2, s3));
        const float e0 = __expf(s0 - m);
        const float e1 = __expf(s1 - m);
        const float e2 = __expf(s2 - m);
        const float e3 = __expf(s3 - m);
        const float iz = oml / ((e0 + e1) + (e2 + e3));

        float l0 = __logf(fmaf(e0, iz, l4));
        float l1 = __logf(fmaf(e1, iz, l4));
        float l2 = __logf(fmaf(e2, iz, l4));
        float l3 = __logf(fmaf(e3, iz, l4));

        const float bcc = sel(same, pers, sw) + __logf(s.tsls + 1.0f);
        const int cc2 = cc ^ 2;
        l0 += sel(i0, bcc, 0.0f) + sel(prev == 0, ab1, 0.0f) + sel(cc2 == 0, ab2, 0.0f);
        l1 += sel(i1, bcc, 0.0f) + sel(prev == 1, ab1, 0.0f) + sel(cc2 == 1, ab2, 0.0f);
        l2 += sel(i2, bcc, 0.0f) + sel(prev == 2, ab1, 0.0f) + sel(cc2 == 2, ab2, 0.0f);
        l3 += sel(i3, bcc, 0.0f) + sel(prev == 3, ab1, 0.0f) + sel(cc2 == 3, ab2, 0.0f);

        *reinterpret_cast<float4*>(&lds[l * ROWB + ti * 16]) = make_float4(l0, l1, l2, l3);
    }

    __syncthreads();
    float4* __restrict__ out4 = reinterpret_cast<float4*>(out);
#pragma unroll
    for (int pp = 0; pp < 16; ++pp) {
        const int ss = pp * 4 + (l >> 4);    // session within group
        const int st = l & 15;               // step within chunk
        const float4 v = *reinterpret_cast<const float4*>(&lds[ss * ROWB + st * 16]);
        out4[((size_t)(grp * 64 + ss)) * T_ + k * CH + st] = v;   // coalesced wave-store
    }
}

// ================= FALLBACK (small ws): pack + monolithic packed scan =================

__global__ __launch_bounds__(64, 1) void castro_scan_packed(
    const unsigned char* __restrict__ pk, const float* __restrict__ p, float* __restrict__ out)
{
    __shared__ unsigned char lds[64 * ROWB];
    const int l = threadIdx.x, blk = blockIdx.x;
    const float beta_r = clipf(sp_(p[0]), 0.01f, 20.0f);
    const float lapse  = clipf(sg_(p[1]), 0.01f, 0.99f);
    const float prior  = clipf(sp_(p[2]), 0.01f, 0.99f);
    const float alpha  = clipf(sg_(p[3]), 0.01f, 0.99f);
    const float decay  = clipf(sg_(p[4]), 0.01f, 0.99f);
    const float ab1 = p[5], ab2 = p[6];
    const float pers = sp_(p[7]), sw = p[8];
    const float gamma = sp_(p[10]);
    const float temp = clipf(sp_(p[11]) + 1e-6f, 1e-6f, 100.0f);
    const float beta_p = sp_(p[12]);
    const float brt = beta_r / temp, l4 = lapse * 0.25f, oml = 1.0f - lapse;
    CS s; s.q0 = s.q1 = s.q2 = s.q3 = prior;
    s.c0 = s.c1 = s.c2 = s.c3 = 0.0f; s.tsls = 0.0f; s.expl = alpha; s.oldc = -1;
    const uint4* pkt = reinterpret_cast<const uint4*>(pk + (size_t)blk * (NCH * 1024)) + l;
    float4* out4 = reinterpret_cast<float4*>(out);
    uint4 cur = pkt[0];
    for (int k = 0; k < NCH; ++k) {
        const uint4 nxt = pkt[(k + 1 < NCH ? k + 1 : k) * 64];
#pragma unroll
        for (int ti = 0; ti < CH; ++ti) {
            const unsigned int word = (ti < 4) ? cur.x : (ti < 8) ? cur.y : (ti < 12) ? cur.z : cur.w;
            const unsigned int byte = (word >> (8 * (ti & 3))) & 0xffu;
            const int prev = s.oldc;
            bool same, i0, i1, i2, i3; int cc;
            step_carry(s, byte, gamma, decay, same, i0, i1, i2, i3, cc);
            const float s0 = fmaf(brt, s.q0, beta_p * __logf(1.0f + s.c0));
            const float s1 = fmaf(brt, s.q1, beta_p * __logf(1.0f + s.c1));
            const float s2 = fmaf(brt, s.q2, beta_p * __logf(1.0f + s.c2));
            const float s3 = fmaf(brt, s.q3, beta_p * __logf(1.0f + s.c3));
            const float m = fmaxf(fmaxf(s0, s1), fmaxf(s2, s3));
            const float e0 = __expf(s0 - m), e1 = __expf(s1 - m);
            const float e2 = __expf(s2 - m), e3 = __expf(s3 - m);
            const float iz = oml / ((e0 + e1) + (e2 + e3));
            float l0 = __logf(fmaf(e0, iz, l4)), l1 = __logf(fmaf(e1, iz, l4));
            float l2 = __logf(fmaf(e2, iz, l4)), l3 = __logf(fmaf(e3, iz, l4));
            const float bcc = sel(same, pers, sw) + __logf(s.tsls + 1.0f);
            const int cc2 = cc ^ 2;
            l0 += sel(i0, bcc, 0.f) + sel(prev == 0, ab1, 0.f) + sel(cc2 == 0, ab2, 0.f);
            l1 += sel(i1, bcc, 0.f) + sel(prev == 1, ab1, 0.f) + sel(cc2 == 1, ab2, 0.f);
            l2 += sel(i2, bcc, 0.f) + sel(prev == 2, ab1, 0.f) + sel(cc2 == 2, ab2, 0.f);
            l3 += sel(i3, bcc, 0.f) + sel(prev == 3, ab1, 0.f) + sel(cc2 == 3, ab2, 0.f);
            *reinterpret_cast<float4*>(&lds[l * ROWB + ti * 16]) = make_float4(l0, l1, l2, l3);
        }
        __syncthreads();
#pragma unroll
        for (int pp = 0; pp < 16; ++pp) {
            const int ss = pp * 4 + (l >> 4);
            const int st = l & 15;
            const float4 v = *reinterpret_cast<const float4*>(&lds[ss * ROWB + st * 16]);
            out4[((size_t)(blk * 64 + ss)) * T_ + k * CH + st] = v;
        }
        __syncthreads();
        cur = nxt;
    }
}

extern "C" void kernel_launch(void* const* d_in, const int* in_sizes, int n_in,
                              void* d_out, int out_size, void* d_ws, size_t ws_size,
                              hipStream_t stream) {
    const float* inputs = (const float*)d_in[0];   // [8192, 512, 8] f32
    const float* params = (const float*)d_in[1];   // [13] f32
    float* out = (float*)d_out;                    // [8192, 512, 4] f32

    if (ws_size >= PACK_BYTES + SNAP_BYTES + CS_BYTES) {
        unsigned char* pk = (unsigned char*)d_ws;
        float4* snap4 = (float4*)((char*)d_ws + PACK_BYTES);
        float4* cs4   = (float4*)((char*)d_ws + PACK_BYTES + SNAP_BYTES);
        pack_kernel<<<dim3((B_ * T_) / 256), dim3(256), 0, stream>>>(inputs, pk);
        chunk_affine2<<<dim3(B_ * NCH / 256), dim3(256), 0, stream>>>(pk, params, cs4);
        boundary_prefix3<<<dim3(B_ / 64), dim3(64), 0, stream>>>(cs4, params, snap4);
        chunk_logits<<<dim3(GRPS * NCH), dim3(64), 0, stream>>>(pk, params, snap4, out);
    } else if (ws_size >= PACK_BYTES) {
        unsigned char* pk = (unsigned char*)d_ws;
        pack_kernel<<<dim3((B_ * T_) / 256), dim3(256), 0, stream>>>(inputs, pk);
        castro_scan_packed<<<dim3(GRPS), dim3(64), 0, stream>>>(pk, params, out);
    }
}

// Round 14
// 92.854 us; speedup vs baseline: 1.0513x; 1.0486x over previous
//
#include <hip/hip_runtime.h>
#include <math.h>

constexpr int B_ = 8192;
constexpr int T_ = 512;
constexpr int CH = 16;                     // steps per chunk / LDS tile
constexpr int NCH = T_ / CH;               // 32 chunks
constexpr int GRPS = B_ / 64;              // 128 session-groups
constexpr int ROWB = CH * 16 + 16;         // 272 B LDS row (pad) for chunk_logits flush
constexpr size_t PACK_BYTES = (size_t)B_ * T_;            // 4 MB
constexpr size_t SN = (size_t)GRPS * NCH * 64;            // 262144 snapshot entries
constexpr size_t SNAP_BYTES = SN * 3 * sizeof(float4);    // 12.6 MB (3 float4 planes)
constexpr size_t CS_BYTES = (size_t)7 * NCH * B_ * sizeof(float4);   // 29.4 MB (7 float4/chunk)

__device__ __forceinline__ float sp_(float x) {
    return fmaxf(x, 0.0f) + log1pf(expf(-fabsf(x)));  // stable softplus
}
__device__ __forceinline__ float sg_(float x) { return 1.0f / (1.0f + expf(-x)); }
__device__ __forceinline__ float clipf(float x, float lo, float hi) { return fminf(fmaxf(x, lo), hi); }
__device__ __forceinline__ float sel(bool c, float a, float b) { return c ? a : b; }

// carry state — all named scalars, statically indexed
struct CS { float q0, q1, q2, q3, c0, c1, c2, c3, tsls, expl; int oldc; };

// One carry step. Shared by all sequential paths -> bit-identical semantics.
__device__ __forceinline__ void step_carry(CS& s, unsigned int byte, float gamma, float decay,
                                           bool& same, bool& i0, bool& i1, bool& i2, bool& i3,
                                           int& cc_out) {
    const int  cc = (int)(byte & 3u);
    const bool rf = (byte & 4u) != 0u;
    const float target = sel(rf, 1.0f, -gamma);          // rv - gamma*(1-rv), rv in {0,1}
    same = (cc == s.oldc);
    s.tsls = sel(same, s.tsls + 1.0f, 0.0f);
    s.expl *= (1.0f - 1e-3f);
    i0 = (cc == 0); i1 = (cc == 1); i2 = (cc == 2); i3 = (cc == 3);
    s.q0 = sel(i0, target, s.q0);  s.c0 += sel(i0, 1.0f, 0.0f);
    s.q1 = sel(i1, target, s.q1);  s.c1 += sel(i1, 1.0f, 0.0f);
    s.q2 = sel(i2, target, s.q2);  s.c2 += sel(i2, 1.0f, 0.0f);
    s.q3 = sel(i3, target, s.q3);  s.c3 += sel(i3, 1.0f, 0.0f);
    const float qm  = 0.25f * ((s.q0 + s.q1) + (s.q2 + s.q3));
    const float omd = (1.0f - s.expl) * decay;
    const float eqd = (s.expl * decay) * qm;
    s.q0 = fmaf(omd, s.q0, eqd);
    s.q1 = fmaf(omd, s.q1, eqd);
    s.q2 = fmaf(omd, s.q2, eqd);
    s.q3 = fmaf(omd, s.q3, eqd);
    s.oldc = cc;
    cc_out = cc;
}

// ================= PRIMARY PATH =================

// ---- pass 1: thread-per-2-steps pack (R10 shape — fastest measured) ----
__global__ __launch_bounds__(256) void pack2(const float* __restrict__ in,
                                             unsigned char* __restrict__ pk) {
    const int tid = blockIdx.x * 256 + threadIdx.x;     // 0 .. B*T/2-1
    const int b   = tid >> 8;                           // session
    const int t2  = tid & 255;                          // step-pair index
    const float4* __restrict__ ip =
        reinterpret_cast<const float4*>(in) + (size_t)b * 1024 + (size_t)t2 * 4;
    const float4 a0 = ip[0];
    const float4 r0 = ip[1];
    const float4 a1 = ip[2];
    const float4 r1 = ip[3];
    const unsigned c0 = (unsigned)(a0.y > 0.5f ? 1 : (a0.z > 0.5f ? 2 : (a0.w > 0.5f ? 3 : 0)))
                      | ((r0.x > 0.5f) ? 4u : 0u);
    const unsigned c1 = (unsigned)(a1.y > 0.5f ? 1 : (a1.z > 0.5f ? 2 : (a1.w > 0.5f ? 3 : 0)))
                      | ((r1.x > 0.5f) ? 4u : 0u);
    // pk layout: ((b>>6)*NCH + tile)*1024 + (b&63)*16 + step_in_chunk
    const int tile = t2 >> 3;            // 8 pairs per 16-step chunk
    const int j    = t2 & 7;             // pair within chunk
    const size_t off = ((size_t)((b >> 6) * NCH + tile)) * 1024 + (size_t)(b & 63) * 16 + j * 2;
    *reinterpret_cast<unsigned short*>(pk + off) = (unsigned short)(c0 | (c1 << 8));
}

// ---- pass 2: SPLIT per-chunk affine: 2 threads per chunk (steps 0-7 / 8-15),
// compose the two 8-step maps via LDS. Halves the serial dep chain, doubles waves. ----
__global__ __launch_bounds__(256, 4) void chunk_affine3(const unsigned char* __restrict__ pk,
                                                        const float* __restrict__ p,
                                                        float4* __restrict__ cs4) {
    __shared__ float xf[128][28];        // odd-half results: 16 M + 4 v + 4 n + lc + run
    const int tid  = threadIdx.x;
    const int gt   = blockIdx.x * 256 + tid;      // 0 .. B*NCH*2-1
    const int half = gt & 1;
    const int sess = (gt >> 1) & 63;
    const int bid  = gt >> 7;                     // grp*NCH + k
    const int k    = bid & (NCH - 1);
    const int grp  = bid >> 5;
    const int b    = grp * 64 + sess;

    const float alpha = clipf(sg_(p[3]), 0.01f, 0.99f);
    const float decay = clipf(sg_(p[4]), 0.01f, 0.99f);
    const float gamma = sp_(p[10]);

    // expl at this half's start: alpha * 0.999^(16k + 8*half)
    float e = alpha * __powf(1.0f - 1e-3f, (float)(CH * k + 8 * half));

    // 8 codes for this half (8 bytes, wave reads 512B contiguous)
    const uint2 cw = *reinterpret_cast<const uint2*>(
        pk + (size_t)bid * 1024 + (size_t)sess * 16 + half * 8);

    float m[4][4], v[4], n[4];
#pragma unroll
    for (int i = 0; i < 4; ++i) {
#pragma unroll
        for (int j = 0; j < 4; ++j) m[i][j] = (i == j) ? 1.0f : 0.0f;
        v[i] = 0.0f; n[i] = 0.0f;
    }
    int prev = -1, run = 0;

#pragma unroll
    for (int ti = 0; ti < 8; ++ti) {
        const unsigned word = (ti < 4) ? cw.x : cw.y;
        const unsigned byte = (word >> (8 * (ti & 3))) & 0xffu;
        const int  cc = (int)(byte & 3u);
        const bool rf = (byte & 4u) != 0u;
        const float tgt = rf ? 1.0f : -gamma;
        e *= (1.0f - 1e-3f);
        run = (cc == prev) ? (run + 1) : 1;
        prev = cc;
        // P: zero row cc of M, overwrite v[cc] = tgt; count action
#pragma unroll
        for (int i = 0; i < 4; ++i) {
            const bool hit = (i == cc);
            v[i] = hit ? tgt : v[i];
            n[i] += hit ? 1.0f : 0.0f;
#pragma unroll
            for (int j = 0; j < 4; ++j) m[i][j] = hit ? 0.0f : m[i][j];
        }
        // S = decay * [(1-e) I + (e/4) J]
        const float aa = decay * (1.0f - e);
        const float bf = decay * e * 0.25f;
        float csum[4];
#pragma unroll
        for (int j = 0; j < 4; ++j) csum[j] = bf * ((m[0][j] + m[1][j]) + (m[2][j] + m[3][j]));
        const float vs = bf * ((v[0] + v[1]) + (v[2] + v[3]));
#pragma unroll
        for (int i = 0; i < 4; ++i) {
#pragma unroll
            for (int j = 0; j < 4; ++j) m[i][j] = fmaf(aa, m[i][j], csum[j]);
            v[i] = fmaf(aa, v[i], vs);
        }
    }

    const int pairrow = tid >> 1;
    if (half == 1) {
#pragma unroll
        for (int i = 0; i < 4; ++i)
#pragma unroll
            for (int j = 0; j < 4; ++j) xf[pairrow][i * 4 + j] = m[i][j];
#pragma unroll
        for (int i = 0; i < 4; ++i) xf[pairrow][16 + i] = v[i];
#pragma unroll
        for (int i = 0; i < 4; ++i) xf[pairrow][20 + i] = n[i];
        xf[pairrow][24] = (float)prev;   // lc_o
        xf[pairrow][25] = (float)run;    // run_o (1..8)
    }
    __syncthreads();

    if (half == 0) {
        float mo[4][4], vo[4], no[4];
#pragma unroll
        for (int i = 0; i < 4; ++i)
#pragma unroll
            for (int j = 0; j < 4; ++j) mo[i][j] = xf[pairrow][i * 4 + j];
#pragma unroll
        for (int i = 0; i < 4; ++i) vo[i] = xf[pairrow][16 + i];
#pragma unroll
        for (int i = 0; i < 4; ++i) no[i] = xf[pairrow][20 + i];
        const float lc_o  = xf[pairrow][24];
        const float run_o = xf[pairrow][25];

        // full chunk = O ∘ E:  Mf = Mo*Me ; vf = Mo*ve + vo ; nf = ne+no
        float mf[4][4], vf[4];
#pragma unroll
        for (int i = 0; i < 4; ++i) {
#pragma unroll
            for (int j = 0; j < 4; ++j)
                mf[i][j] = fmaf(mo[i][0], m[0][j], fmaf(mo[i][1], m[1][j],
                           fmaf(mo[i][2], m[2][j], mo[i][3] * m[3][j])));
            vf[i] = fmaf(mo[i][0], v[0], fmaf(mo[i][1], v[1],
                    fmaf(mo[i][2], v[2], fmaf(mo[i][3], v[3], vo[i]))));
        }
        // trailing run of concat: run_o if run_o<8; else 8 + (lc_e==lc_o ? run_e : 0)
        const float runf = run_o + ((run_o == 8.0f && (float)prev == lc_o) ? (float)run : 0.0f);

        cs4[((size_t)k * 7 + 0) * B_ + b] = make_float4(mf[0][0], mf[0][1], mf[0][2], mf[0][3]);
        cs4[((size_t)k * 7 + 1) * B_ + b] = make_float4(mf[1][0], mf[1][1], mf[1][2], mf[1][3]);
        cs4[((size_t)k * 7 + 2) * B_ + b] = make_float4(mf[2][0], mf[2][1], mf[2][2], mf[2][3]);
        cs4[((size_t)k * 7 + 3) * B_ + b] = make_float4(mf[3][0], mf[3][1], mf[3][2], mf[3][3]);
        cs4[((size_t)k * 7 + 4) * B_ + b] = make_float4(vf[0], vf[1], vf[2], vf[3]);
        cs4[((size_t)k * 7 + 5) * B_ + b] = make_float4(n[0] + no[0], n[1] + no[1],
                                                        n[2] + no[2], n[3] + no[3]);
        cs4[((size_t)k * 7 + 6) * B_ + b] = make_float4(lc_o, runf, 0.0f, 0.0f);
    }
}

// ---- pass 3: boundary prefix, 128 blocks x 64 thr, float4 loads, depth-2 pipeline ----
__global__ __launch_bounds__(64, 1) void boundary_prefix3(const float4* __restrict__ cs4,
                                                          const float* __restrict__ p,
                                                          float4* __restrict__ snap4) {
    const int b   = blockIdx.x * 64 + threadIdx.x;   // session
    const int grp = b >> 6;
    const int l   = b & 63;

    const float prior = clipf(sp_(p[2]), 0.01f, 0.99f);
    const float alpha = clipf(sg_(p[3]), 0.01f, 0.99f);

    float q[4], c[4];
#pragma unroll
    for (int i = 0; i < 4; ++i) { q[i] = prior; c[i] = 0.0f; }
    float e = alpha;
    float ER = 0.0f;
    float lcprev = -1.0f;
    float tsls = 0.0f;

    float4 buf[3][7];   // depth-2 pipeline; static indices under full unroll
#pragma unroll
    for (int j = 0; j < 7; ++j) buf[0][j] = cs4[((size_t)0 * 7 + j) * B_ + b];
#pragma unroll
    for (int j = 0; j < 7; ++j) buf[1][j] = cs4[((size_t)1 * 7 + j) * B_ + b];

#pragma unroll
    for (int k = 0; k < NCH; ++k) {
        if (k + 2 < NCH) {
#pragma unroll
            for (int j = 0; j < 7; ++j)
                buf[(k + 2) % 3][j] = cs4[((size_t)(k + 2) * 7 + j) * B_ + b];
        }

        // snapshot = state BEFORE chunk k (exact sequential e chain preserved)
        const size_t sb = (size_t)(grp * NCH + k) * 64 + l;
        snap4[0 * SN + sb] = make_float4(q[0], q[1], q[2], q[3]);
        snap4[1 * SN + sb] = make_float4(c[0], c[1], c[2], c[3]);
        snap4[2 * SN + sb] = make_float4(tsls, e, lcprev, 0.0f);

        // q <- M q + v ; c += n
        const float4 m0 = buf[k % 3][0], m1 = buf[k % 3][1];
        const float4 m2 = buf[k % 3][2], m3 = buf[k % 3][3];
        const float4 vv = buf[k % 3][4], nn = buf[k % 3][5];
        const float4 mt = buf[k % 3][6];
        float nq0 = fmaf(m0.x, q[0], fmaf(m0.y, q[1], fmaf(m0.z, q[2], fmaf(m0.w, q[3], vv.x))));
        float nq1 = fmaf(m1.x, q[0], fmaf(m1.y, q[1], fmaf(m1.z, q[2], fmaf(m1.w, q[3], vv.y))));
        float nq2 = fmaf(m2.x, q[0], fmaf(m2.y, q[1], fmaf(m2.z, q[2], fmaf(m2.w, q[3], vv.z))));
        float nq3 = fmaf(m3.x, q[0], fmaf(m3.y, q[1], fmaf(m3.z, q[2], fmaf(m3.w, q[3], vv.w))));
        q[0] = nq0; q[1] = nq1; q[2] = nq2; q[3] = nq3;
        c[0] += nn.x; c[1] += nn.y; c[2] += nn.z; c[3] += nn.w;

        const float lc = mt.x, run = mt.y;
        ER = (run == 16.0f && lc == lcprev) ? (ER + 16.0f) : run;
        tsls = ER - 1.0f;
        lcprev = lc;

#pragma unroll
        for (int i = 0; i < CH; ++i) e *= (1.0f - 1e-3f);
    }
}

// ---- pass 4: per-chunk logits, float4 snap loads (unchanged, proven) ----
__global__ __launch_bounds__(64) void chunk_logits(const unsigned char* __restrict__ pk,
                                                   const float* __restrict__ p,
                                                   const float4* __restrict__ snap4,
                                                   float* __restrict__ out) {
    __shared__ unsigned char lds[64 * ROWB];
    const int l   = threadIdx.x;
    const int bid = blockIdx.x;          // = grp*NCH + k
    const int k   = bid & (NCH - 1);
    const int grp = bid >> 5;            // NCH == 32

    const float beta_r = clipf(sp_(p[0]), 0.01f, 20.0f);
    const float lapse  = clipf(sg_(p[1]), 0.01f, 0.99f);
    const float decay  = clipf(sg_(p[4]), 0.01f, 0.99f);
    const float ab1    = p[5];
    const float ab2    = p[6];
    const float pers   = sp_(p[7]);
    const float sw     = p[8];
    const float gamma  = sp_(p[10]);
    const float temp   = clipf(sp_(p[11]) + 1e-6f, 1e-6f, 100.0f);
    const float beta_p = sp_(p[12]);
    const float brt = beta_r / temp;
    const float l4  = lapse * 0.25f;
    const float oml = 1.0f - lapse;

    const size_t sb = (size_t)bid * 64 + l;
    const float4 qv = snap4[0 * SN + sb];
    const float4 cv = snap4[1 * SN + sb];
    const float4 mv = snap4[2 * SN + sb];
    CS s;
    s.q0 = qv.x; s.q1 = qv.y; s.q2 = qv.z; s.q3 = qv.w;
    s.c0 = cv.x; s.c1 = cv.y; s.c2 = cv.z; s.c3 = cv.w;
    s.tsls = mv.x; s.expl = mv.y; s.oldc = (int)mv.z;

    const uint4 cur = reinterpret_cast<const uint4*>(pk)[(size_t)bid * 64 + l];

#pragma unroll
    for (int ti = 0; ti < CH; ++ti) {
        const unsigned int word = (ti < 4) ? cur.x : (ti < 8) ? cur.y : (ti < 12) ? cur.z : cur.w;
        const unsigned int byte = (word >> (8 * (ti & 3))) & 0xffu;
        const int prev = s.oldc;
        bool same, i0, i1, i2, i3; int cc;
        step_carry(s, byte, gamma, decay, same, i0, i1, i2, i3, cc);

        const float s0 = fmaf(brt, s.q0, beta_p * __logf(1.0f + s.c0));
        const float s1 = fmaf(brt, s.q1, beta_p * __logf(1.0f + s.c1));
        const float s2 = fmaf(brt, s.q2, beta_p * __logf(1.0f + s.c2));
        const float s3 = fmaf(brt, s.q3, beta_p * __logf(1.0f + s.c3));
        const float m  = fmaxf(fmaxf(s0, s1), fmaxf(s2, s3));
        const float e0 = __expf(s0 - m);
        const float e1 = __expf(s1 - m);
        const float e2 = __expf(s2 - m);
        const float e3 = __expf(s3 - m);
        const float iz = oml / ((e0 + e1) + (e2 + e3));

        float l0 = __logf(fmaf(e0, iz, l4));
        float l1 = __logf(fmaf(e1, iz, l4));
        float l2 = __logf(fmaf(e2, iz, l4));
        float l3 = __logf(fmaf(e3, iz, l4));

        const float bcc = sel(same, pers, sw) + __logf(s.tsls + 1.0f);
        const int cc2 = cc ^ 2;
        l0 += sel(i0, bcc, 0.0f) + sel(prev == 0, ab1, 0.0f) + sel(cc2 == 0, ab2, 0.0f);
        l1 += sel(i1, bcc, 0.0f) + sel(prev == 1, ab1, 0.0f) + sel(cc2 == 1, ab2, 0.0f);
        l2 += sel(i2, bcc, 0.0f) + sel(prev == 2, ab1, 0.0f) + sel(cc2 == 2, ab2, 0.0f);
        l3 += sel(i3, bcc, 0.0f) + sel(prev == 3, ab1, 0.0f) + sel(cc2 == 3, ab2, 0.0f);

        *reinterpret_cast<float4*>(&lds[l * ROWB + ti * 16]) = make_float4(l0, l1, l2, l3);
    }

    __syncthreads();
    float4* __restrict__ out4 = reinterpret_cast<float4*>(out);
#pragma unroll
    for (int pp = 0; pp < 16; ++pp) {
        const int ss = pp * 4 + (l >> 4);    // session within group
        const int st = l & 15;               // step within chunk
        const float4 v = *reinterpret_cast<const float4*>(&lds[ss * ROWB + st * 16]);
        out4[((size_t)(grp * 64 + ss)) * T_ + k * CH + st] = v;   // coalesced wave-store
    }
}

// ================= FALLBACK (small ws): pack + monolithic packed scan =================

__global__ __launch_bounds__(256) void pack_kernel(const float* __restrict__ in,
                                                   unsigned char* __restrict__ pk) {
    const int tid  = blockIdx.x * 256 + threadIdx.x;      // 0 .. B*T-1
    const int ti   = tid & 15;
    const int lane = (tid >> 4) & 63;
    const int tile = (tid >> 10) & (NCH - 1);
    const int grp  = tid >> 15;
    const int b = (grp << 6) | lane;
    const int t = (tile << 4) | ti;
    const float* base = in + ((size_t)b * T_ + t) * 8;
    const float4 a = *reinterpret_cast<const float4*>(base);
    const float  r = base[4];
    const int cc = a.y > 0.5f ? 1 : (a.z > 0.5f ? 2 : (a.w > 0.5f ? 3 : 0));
    pk[tid] = (unsigned char)(cc | ((r > 0.5f) ? 4 : 0));
}

__global__ __launch_bounds__(64, 1) void castro_scan_packed(
    const unsigned char* __restrict__ pk, const float* __restrict__ p, float* __restrict__ out)
{
    __shared__ unsigned char lds[64 * ROWB];
    const int l = threadIdx.x, blk = blockIdx.x;
    const float beta_r = clipf(sp_(p[0]), 0.01f, 20.0f);
    const float lapse  = clipf(sg_(p[1]), 0.01f, 0.99f);
    const float prior  = clipf(sp_(p[2]), 0.01f, 0.99f);
    const float alpha  = clipf(sg_(p[3]), 0.01f, 0.99f);
    const float decay  = clipf(sg_(p[4]), 0.01f, 0.99f);
    const float ab1 = p[5], ab2 = p[6];
    const float pers = sp_(p[7]), sw = p[8];
    const float gamma = sp_(p[10]);
    const float temp = clipf(sp_(p[11]) + 1e-6f, 1e-6f, 100.0f);
    const float beta_p = sp_(p[12]);
    const float brt = beta_r / temp, l4 = lapse * 0.25f, oml = 1.0f - lapse;
    CS s; s.q0 = s.q1 = s.q2 = s.q3 = prior;
    s.c0 = s.c1 = s.c2 = s.c3 = 0.0f; s.tsls = 0.0f; s.expl = alpha; s.oldc = -1;
    const uint4* pkt = reinterpret_cast<const uint4*>(pk + (size_t)blk * (NCH * 1024)) + l;
    float4* out4 = reinterpret_cast<float4*>(out);
    uint4 cur = pkt[0];
    for (int k = 0; k < NCH; ++k) {
        const uint4 nxt = pkt[(k + 1 < NCH ? k + 1 : k) * 64];
#pragma unroll
        for (int ti = 0; ti < CH; ++ti) {
            const unsigned int word = (ti < 4) ? cur.x : (ti < 8) ? cur.y : (ti < 12) ? cur.z : cur.w;
            const unsigned int byte = (word >> (8 * (ti & 3))) & 0xffu;
            const int prev = s.oldc;
            bool same, i0, i1, i2, i3; int cc;
            step_carry(s, byte, gamma, decay, same, i0, i1, i2, i3, cc);
            const float s0 = fmaf(brt, s.q0, beta_p * __logf(1.0f + s.c0));
            const float s1 = fmaf(brt, s.q1, beta_p * __logf(1.0f + s.c1));
            const float s2 = fmaf(brt, s.q2, beta_p * __logf(1.0f + s.c2));
            const float s3 = fmaf(brt, s.q3, beta_p * __logf(1.0f + s.c3));
            const float m = fmaxf(fmaxf(s0, s1), fmaxf(s2, s3));
            const float e0 = __expf(s0 - m), e1 = __expf(s1 - m);
            const float e2 = __expf(s2 - m), e3 = __expf(s3 - m);
            const float iz = oml / ((e0 + e1) + (e2 + e3));
            float l0 = __logf(fmaf(e0, iz, l4)), l1 = __logf(fmaf(e1, iz, l4));
            float l2 = __logf(fmaf(e2, iz, l4)), l3 = __logf(fmaf(e3, iz, l4));
            const float bcc = sel(same, pers, sw) + __logf(s.tsls + 1.0f);
            const int cc2 = cc ^ 2;
            l0 += sel(i0, bcc, 0.f) + sel(prev == 0, ab1, 0.f) + sel(cc2 == 0, ab2, 0.f);
            l1 += sel(i1, bcc, 0.f) + sel(prev == 1, ab1, 0.f) + sel(cc2 == 1, ab2, 0.f);
            l2 += sel(i2, bcc, 0.f) + sel(prev == 2, ab1, 0.f) + sel(cc2 == 2, ab2, 0.f);
            l3 += sel(i3, bcc, 0.f) + sel(prev == 3, ab1, 0.f) + sel(cc2 == 3, ab2, 0.f);
            *reinterpret_cast<float4*>(&lds[l * ROWB + ti * 16]) = make_float4(l0, l1, l2, l3);
        }
        __syncthreads();
#pragma unroll
        for (int pp = 0; pp < 16; ++pp) {
            const int ss = pp * 4 + (l >> 4);
            const int st = l & 15;
            const float4 v = *reinterpret_cast<const float4*>(&lds[ss * ROWB + st * 16]);
            out4[((size_t)(blk * 64 + ss)) * T_ + k * CH + st] = v;
        }
        __syncthreads();
        cur = nxt;
    }
}

extern "C" void kernel_launch(void* const* d_in, const int* in_sizes, int n_in,
                              void* d_out, int out_size, void* d_ws, size_t ws_size,
                              hipStream_t stream) {
    const float* inputs = (const float*)d_in[0];   // [8192, 512, 8] f32
    const float* params = (const float*)d_in[1];   // [13] f32
    float* out = (float*)d_out;                    // [8192, 512, 4] f32

    if (ws_size >= PACK_BYTES + SNAP_BYTES + CS_BYTES) {
        unsigned char* pk = (unsigned char*)d_ws;
        float4* snap4 = (float4*)((char*)d_ws + PACK_BYTES);
        float4* cs4   = (float4*)((char*)d_ws + PACK_BYTES + SNAP_BYTES);
        pack2<<<dim3(B_ * T_ / 2 / 256), dim3(256), 0, stream>>>(inputs, pk);
        chunk_affine3<<<dim3(B_ * NCH * 2 / 256), dim3(256), 0, stream>>>(pk, params, cs4);
        boundary_prefix3<<<dim3(B_ / 64), dim3(64), 0, stream>>>(cs4, params, snap4);
        chunk_logits<<<dim3(GRPS * NCH), dim3(64), 0, stream>>>(pk, params, snap4, out);
    } else if (ws_size >= PACK_BYTES) {
        unsigned char* pk = (unsigned char*)d_ws;
        pack_kernel<<<dim3((B_ * T_) / 256), dim3(256), 0, stream>>>(inputs, pk);
        castro_scan_packed<<<dim3(GRPS), dim3(64), 0, stream>>>(pk, params, out);
    }
}

// Round 15
// 87.825 us; speedup vs baseline: 1.1115x; 1.0573x over previous
//
#include <hip/hip_runtime.h>
#include <math.h>

constexpr int B_ = 8192;
constexpr int T_ = 512;
constexpr int CH = 16;                     // steps per chunk / LDS tile
constexpr int NCH = T_ / CH;               // 32 chunks
constexpr int GRPS = B_ / 64;              // 128 session-groups
constexpr int ROWB = CH * 16 + 16;         // 272 B LDS row (pad) for chunk_logits flush
constexpr size_t PACK_BYTES = (size_t)B_ * T_;            // 4 MB
constexpr size_t SN = (size_t)GRPS * NCH * 64;            // 262144 snapshot entries
constexpr size_t SNAP_BYTES = SN * 3 * sizeof(float4);    // 12.6 MB (3 float4 planes)

__device__ __forceinline__ float sp_(float x) {
    return fmaxf(x, 0.0f) + log1pf(expf(-fabsf(x)));  // stable softplus
}
__device__ __forceinline__ float sg_(float x) { return 1.0f / (1.0f + expf(-x)); }
__device__ __forceinline__ float clipf(float x, float lo, float hi) { return fminf(fmaxf(x, lo), hi); }
__device__ __forceinline__ float sel(bool c, float a, float b) { return c ? a : b; }

// carry state — all named scalars, statically indexed
struct CS { float q0, q1, q2, q3, c0, c1, c2, c3, tsls, expl; int oldc; };

// One carry step. Shared by all sequential paths -> bit-identical semantics.
__device__ __forceinline__ void step_carry(CS& s, unsigned int byte, float gamma, float decay,
                                           bool& same, bool& i0, bool& i1, bool& i2, bool& i3,
                                           int& cc_out) {
    const int  cc = (int)(byte & 3u);
    const bool rf = (byte & 4u) != 0u;
    const float target = sel(rf, 1.0f, -gamma);          // rv - gamma*(1-rv), rv in {0,1}
    same = (cc == s.oldc);
    s.tsls = sel(same, s.tsls + 1.0f, 0.0f);
    s.expl *= (1.0f - 1e-3f);
    i0 = (cc == 0); i1 = (cc == 1); i2 = (cc == 2); i3 = (cc == 3);
    s.q0 = sel(i0, target, s.q0);  s.c0 += sel(i0, 1.0f, 0.0f);
    s.q1 = sel(i1, target, s.q1);  s.c1 += sel(i1, 1.0f, 0.0f);
    s.q2 = sel(i2, target, s.q2);  s.c2 += sel(i2, 1.0f, 0.0f);
    s.q3 = sel(i3, target, s.q3);  s.c3 += sel(i3, 1.0f, 0.0f);
    const float qm  = 0.25f * ((s.q0 + s.q1) + (s.q2 + s.q3));
    const float omd = (1.0f - s.expl) * decay;
    const float eqd = (s.expl * decay) * qm;
    s.q0 = fmaf(omd, s.q0, eqd);
    s.q1 = fmaf(omd, s.q1, eqd);
    s.q2 = fmaf(omd, s.q2, eqd);
    s.q3 = fmaf(omd, s.q3, eqd);
    s.oldc = cc;
    cc_out = cc;
}

// ================= PRIMARY PATH =================

// ---- pass 1: thread-per-step pack (R3/R5-proven shape, ~28 µs) ----
__global__ __launch_bounds__(256) void pack_kernel(const float* __restrict__ in,
                                                   unsigned char* __restrict__ pk) {
    const int tid  = blockIdx.x * 256 + threadIdx.x;      // 0 .. B*T-1
    const int ti   = tid & 15;
    const int lane = (tid >> 4) & 63;
    const int tile = (tid >> 10) & (NCH - 1);
    const int grp  = tid >> 15;
    const int b = (grp << 6) | lane;
    const int t = (tile << 4) | ti;
    const float* base = in + ((size_t)b * T_ + t) * 8;
    const float4 a = *reinterpret_cast<const float4*>(base);
    const float  r = base[4];
    const int cc = a.y > 0.5f ? 1 : (a.z > 0.5f ? 2 : (a.w > 0.5f ? 3 : 0));
    pk[tid] = (unsigned char)(cc | ((r > 0.5f) ? 4 : 0));
}

// ---- pass 2: fused chunk-map + wave-scan + snapshot. Lane k of a 32-lane group owns
// chunk k of one session; Hillis-Steele shuffle scan composes the affine maps; cum/tsls
// scans are bit-exact integer arithmetic. Replaces chunk_affine + boundary_prefix + cs4. ----
__global__ __launch_bounds__(256) void scan_snap(const unsigned char* __restrict__ pk,
                                                 const float* __restrict__ p,
                                                 float4* __restrict__ snap4) {
    const int tid  = threadIdx.x;
    const int w    = tid >> 6;            // wave 0..3
    const int lane = tid & 63;
    const int k    = lane & 31;           // chunk index
    const int b    = blockIdx.x * 8 + w * 2 + (lane >> 5);   // session
    const int grp  = b >> 6;
    const int sl   = b & 63;

    const float prior = clipf(sp_(p[2]), 0.01f, 0.99f);
    const float alpha = clipf(sg_(p[3]), 0.01f, 0.99f);
    const float decay = clipf(sg_(p[4]), 0.01f, 0.99f);
    const float gamma = sp_(p[10]);

    // e at chunk start (feeds both map build and the snapshot)
    const float e0k = alpha * __powf(1.0f - 1e-3f, (float)(CH * k));

    const uint4 cw = reinterpret_cast<const uint4*>(pk)[(size_t)(grp * NCH + k) * 64 + sl];

    // ---- build this chunk's affine map (M, v), counts n, last-cc, trailing run ----
    float m[4][4], v[4], n[4];
#pragma unroll
    for (int i = 0; i < 4; ++i) {
#pragma unroll
        for (int j = 0; j < 4; ++j) m[i][j] = (i == j) ? 1.0f : 0.0f;
        v[i] = 0.0f; n[i] = 0.0f;
    }
    int prev = -1, run = 0;
    float e = e0k;

#pragma unroll
    for (int ti = 0; ti < CH; ++ti) {
        const unsigned word = (ti < 4) ? cw.x : (ti < 8) ? cw.y : (ti < 12) ? cw.z : cw.w;
        const unsigned byte = (word >> (8 * (ti & 3))) & 0xffu;
        const int  cc = (int)(byte & 3u);
        const bool rf = (byte & 4u) != 0u;
        const float tgt = rf ? 1.0f : -gamma;
        e *= (1.0f - 1e-3f);
        run = (cc == prev) ? (run + 1) : 1;
        prev = cc;
#pragma unroll
        for (int i = 0; i < 4; ++i) {
            const bool hit = (i == cc);
            v[i] = hit ? tgt : v[i];
            n[i] += hit ? 1.0f : 0.0f;
#pragma unroll
            for (int j = 0; j < 4; ++j) m[i][j] = hit ? 0.0f : m[i][j];
        }
        const float aa = decay * (1.0f - e);
        const float bf = decay * e * 0.25f;
        float csum[4];
#pragma unroll
        for (int j = 0; j < 4; ++j) csum[j] = bf * ((m[0][j] + m[1][j]) + (m[2][j] + m[3][j]));
        const float vs = bf * ((v[0] + v[1]) + (v[2] + v[3]));
#pragma unroll
        for (int i = 0; i < 4; ++i) {
#pragma unroll
            for (int j = 0; j < 4; ++j) m[i][j] = fmaf(aa, m[i][j], csum[j]);
            v[i] = fmaf(aa, v[i], vs);
        }
    }

    // ---- inclusive shuffle-scan of (M,v) over k (compose: cur ∘ prev) ----
    float sm[4][4], sv[4];
#pragma unroll
    for (int i = 0; i < 4; ++i) {
#pragma unroll
        for (int j = 0; j < 4; ++j) sm[i][j] = m[i][j];
        sv[i] = v[i];
    }
#pragma unroll
    for (int d = 1; d < 32; d <<= 1) {
        float pm[4][4], pv[4];
#pragma unroll
        for (int i = 0; i < 4; ++i) {
#pragma unroll
            for (int j = 0; j < 4; ++j) pm[i][j] = __shfl_up(sm[i][j], d, 32);
            pv[i] = __shfl_up(sv[i], d, 32);
        }
        if (k >= d) {
            float nm[4][4], nv[4];
#pragma unroll
            for (int i = 0; i < 4; ++i) {
#pragma unroll
                for (int j = 0; j < 4; ++j)
                    nm[i][j] = fmaf(sm[i][0], pm[0][j], fmaf(sm[i][1], pm[1][j],
                               fmaf(sm[i][2], pm[2][j], sm[i][3] * pm[3][j])));
                nv[i] = fmaf(sm[i][0], pv[0], fmaf(sm[i][1], pv[1],
                        fmaf(sm[i][2], pv[2], fmaf(sm[i][3], pv[3], sv[i]))));
            }
#pragma unroll
            for (int i = 0; i < 4; ++i) {
#pragma unroll
                for (int j = 0; j < 4; ++j) sm[i][j] = nm[i][j];
                sv[i] = nv[i];
            }
        }
    }

    // exclusive map for chunk k = inclusive of k-1 (lane 0: identity)
    float q[4];
#pragma unroll
    for (int i = 0; i < 4; ++i) {
        float er0 = __shfl_up(sm[i][0], 1, 32);
        float er1 = __shfl_up(sm[i][1], 1, 32);
        float er2 = __shfl_up(sm[i][2], 1, 32);
        float er3 = __shfl_up(sm[i][3], 1, 32);
        float ev  = __shfl_up(sv[i], 1, 32);
        if (k == 0) { er0 = (i == 0); er1 = (i == 1); er2 = (i == 2); er3 = (i == 3); ev = 0.0f; }
        q[i] = fmaf(prior, ((er0 + er1) + (er2 + er3)), ev);
    }

    // ---- cum counts: exclusive prefix sum (bit-exact) ----
    float cex[4];
#pragma unroll
    for (int i = 0; i < 4; ++i) {
        float s = n[i];
#pragma unroll
        for (int d = 1; d < 32; d <<= 1) {
            const float t = __shfl_up(s, d, 32);
            if (k >= d) s += t;
        }
        cex[i] = s - n[i];
    }

    // ---- tsls via trailing-run scan (bit-exact) ----
    const float lcf  = (float)prev;
    const float runf = (float)run;
    float lcm1 = __shfl_up(lcf, 1, 32);
    if (k == 0) lcm1 = -1.0f;
    const bool u = (runf == 16.0f) && (lcf == lcm1);
    const unsigned long long bal = __ballot(u);
    const unsigned gm = (unsigned)(bal >> (lane & 32));
    const unsigned vsh = (k == 31) ? gm : (gm << (31 - k));
    const int c = __clz(~vsh);                        // trailing consecutive u's ending at k
    const float runsrc = __shfl(runf, (lane & 32) + (k - c));
    const float TR = 16.0f * (float)c + runsrc;       // trailing run at end of chunk k
    float TRm1 = __shfl_up(TR, 1, 32);
    const float tsls = (k == 0) ? 0.0f : (TRm1 - 1.0f);
    const float lcprev = (k == 0) ? -1.0f : lcm1;

    // ---- snapshot write (layout chunk_logits expects) ----
    const size_t sb = (size_t)(grp * NCH + k) * 64 + sl;
    snap4[0 * SN + sb] = make_float4(q[0], q[1], q[2], q[3]);
    snap4[1 * SN + sb] = make_float4(cex[0], cex[1], cex[2], cex[3]);
    snap4[2 * SN + sb] = make_float4(tsls, e0k, lcprev, 0.0f);
}

// ---- pass 3: per-chunk logits, float4 snap loads (unchanged, proven) ----
__global__ __launch_bounds__(64) void chunk_logits(const unsigned char* __restrict__ pk,
                                                   const float* __restrict__ p,
                                                   const float4* __restrict__ snap4,
                                                   float* __restrict__ out) {
    __shared__ unsigned char lds[64 * ROWB];
    const int l   = threadIdx.x;
    const int bid = blockIdx.x;          // = grp*NCH + k
    const int k   = bid & (NCH - 1);
    const int grp = bid >> 5;            // NCH == 32

    const float beta_r = clipf(sp_(p[0]), 0.01f, 20.0f);
    const float lapse  = clipf(sg_(p[1]), 0.01f, 0.99f);
    const float decay  = clipf(sg_(p[4]), 0.01f, 0.99f);
    const float ab1    = p[5];
    const float ab2    = p[6];
    const float pers   = sp_(p[7]);
    const float sw     = p[8];
    const float gamma  = sp_(p[10]);
    const float temp   = clipf(sp_(p[11]) + 1e-6f, 1e-6f, 100.0f);
    const float beta_p = sp_(p[12]);
    const float brt = beta_r / temp;
    const float l4  = lapse * 0.25f;
    const float oml = 1.0f - lapse;

    const size_t sb = (size_t)bid * 64 + l;
    const float4 qv = snap4[0 * SN + sb];
    const float4 cv = snap4[1 * SN + sb];
    const float4 mv = snap4[2 * SN + sb];
    CS s;
    s.q0 = qv.x; s.q1 = qv.y; s.q2 = qv.z; s.q3 = qv.w;
    s.c0 = cv.x; s.c1 = cv.y; s.c2 = cv.z; s.c3 = cv.w;
    s.tsls = mv.x; s.expl = mv.y; s.oldc = (int)mv.z;

    const uint4 cur = reinterpret_cast<const uint4*>(pk)[(size_t)bid * 64 + l];

#pragma unroll
    for (int ti = 0; ti < CH; ++ti) {
        const unsigned int word = (ti < 4) ? cur.x : (ti < 8) ? cur.y : (ti < 12) ? cur.z : cur.w;
        const unsigned int byte = (word >> (8 * (ti & 3))) & 0xffu;
        const int prev = s.oldc;
        bool same, i0, i1, i2, i3; int cc;
        step_carry(s, byte, gamma, decay, same, i0, i1, i2, i3, cc);

        const float s0 = fmaf(brt, s.q0, beta_p * __logf(1.0f + s.c0));
        const float s1 = fmaf(brt, s.q1, beta_p * __logf(1.0f + s.c1));
        const float s2 = fmaf(brt, s.q2, beta_p * __logf(1.0f + s.c2));
        const float s3 = fmaf(brt, s.q3, beta_p * __logf(1.0f + s.c3));
        const float m  = fmaxf(fmaxf(s0, s1), fmaxf(s2, s3));
        const float e0 = __expf(s0 - m);
        const float e1 = __expf(s1 - m);
        const float e2 = __expf(s2 - m);
        const float e3 = __expf(s3 - m);
        const float iz = oml / ((e0 + e1) + (e2 + e3));

        float l0 = __logf(fmaf(e0, iz, l4));
        float l1 = __logf(fmaf(e1, iz, l4));
        float l2 = __logf(fmaf(e2, iz, l4));
        float l3 = __logf(fmaf(e3, iz, l4));

        const float bcc = sel(same, pers, sw) + __logf(s.tsls + 1.0f);
        const int cc2 = cc ^ 2;
        l0 += sel(i0, bcc, 0.0f) + sel(prev == 0, ab1, 0.0f) + sel(cc2 == 0, ab2, 0.0f);
        l1 += sel(i1, bcc, 0.0f) + sel(prev == 1, ab1, 0.0f) + sel(cc2 == 1, ab2, 0.0f);
        l2 += sel(i2, bcc, 0.0f) + sel(prev == 2, ab1, 0.0f) + sel(cc2 == 2, ab2, 0.0f);
        l3 += sel(i3, bcc, 0.0f) + sel(prev == 3, ab1, 0.0f) + sel(cc2 == 3, ab2, 0.0f);

        *reinterpret_cast<float4*>(&lds[l * ROWB + ti * 16]) = make_float4(l0, l1, l2, l3);
    }

    __syncthreads();
    float4* __restrict__ out4 = reinterpret_cast<float4*>(out);
#pragma unroll
    for (int pp = 0; pp < 16; ++pp) {
        const int ss = pp * 4 + (l >> 4);    // session within group
        const int st = l & 15;               // step within chunk
        const float4 v = *reinterpret_cast<const float4*>(&lds[ss * ROWB + st * 16]);
        out4[((size_t)(grp * 64 + ss)) * T_ + k * CH + st] = v;   // coalesced wave-store
    }
}

// ================= FALLBACK (small ws): pack + monolithic packed scan =================

__global__ __launch_bounds__(64, 1) void castro_scan_packed(
    const unsigned char* __restrict__ pk, const float* __restrict__ p, float* __restrict__ out)
{
    __shared__ unsigned char lds[64 * ROWB];
    const int l = threadIdx.x, blk = blockIdx.x;
    const float beta_r = clipf(sp_(p[0]), 0.01f, 20.0f);
    const float lapse  = clipf(sg_(p[1]), 0.01f, 0.99f);
    const float prior  = clipf(sp_(p[2]), 0.01f, 0.99f);
    const float alpha  = clipf(sg_(p[3]), 0.01f, 0.99f);
    const float decay  = clipf(sg_(p[4]), 0.01f, 0.99f);
    const float ab1 = p[5], ab2 = p[6];
    const float pers = sp_(p[7]), sw = p[8];
    const float gamma = sp_(p[10]);
    const float temp = clipf(sp_(p[11]) + 1e-6f, 1e-6f, 100.0f);
    const float beta_p = sp_(p[12]);
    const float brt = beta_r / temp, l4 = lapse * 0.25f, oml = 1.0f - lapse;
    CS s; s.q0 = s.q1 = s.q2 = s.q3 = prior;
    s.c0 = s.c1 = s.c2 = s.c3 = 0.0f; s.tsls = 0.0f; s.expl = alpha; s.oldc = -1;
    const uint4* pkt = reinterpret_cast<const uint4*>(pk + (size_t)blk * (NCH * 1024)) + l;
    float4* out4 = reinterpret_cast<float4*>(out);
    uint4 cur = pkt[0];
    for (int k = 0; k < NCH; ++k) {
        const uint4 nxt = pkt[(k + 1 < NCH ? k + 1 : k) * 64];
#pragma unroll
        for (int ti = 0; ti < CH; ++ti) {
            const unsigned int word = (ti < 4) ? cur.x : (ti < 8) ? cur.y : (ti < 12) ? cur.z : cur.w;
            const unsigned int byte = (word >> (8 * (ti & 3))) & 0xffu;
            const int prev = s.oldc;
            bool same, i0, i1, i2, i3; int cc;
            step_carry(s, byte, gamma, decay, same, i0, i1, i2, i3, cc);
            const float s0 = fmaf(brt, s.q0, beta_p * __logf(1.0f + s.c0));
            const float s1 = fmaf(brt, s.q1, beta_p * __logf(1.0f + s.c1));
            const float s2 = fmaf(brt, s.q2, beta_p * __logf(1.0f + s.c2));
            const float s3 = fmaf(brt, s.q3, beta_p * __logf(1.0f + s.c3));
            const float m = fmaxf(fmaxf(s0, s1), fmaxf(s2, s3));
            const float e0 = __expf(s0 - m), e1 = __expf(s1 - m);
            const float e2 = __expf(s2 - m), e3 = __expf(s3 - m);
            const float iz = oml / ((e0 + e1) + (e2 + e3));
            float l0 = __logf(fmaf(e0, iz, l4)), l1 = __logf(fmaf(e1, iz, l4));
            float l2 = __logf(fmaf(e2, iz, l4)), l3 = __logf(fmaf(e3, iz, l4));
            const float bcc = sel(same, pers, sw) + __logf(s.tsls + 1.0f);
            const int cc2 = cc ^ 2;
            l0 += sel(i0, bcc, 0.f) + sel(prev == 0, ab1, 0.f) + sel(cc2 == 0, ab2, 0.f);
            l1 += sel(i1, bcc, 0.f) + sel(prev == 1, ab1, 0.f) + sel(cc2 == 1, ab2, 0.f);
            l2 += sel(i2, bcc, 0.f) + sel(prev == 2, ab1, 0.f) + sel(cc2 == 2, ab2, 0.f);
            l3 += sel(i3, bcc, 0.f) + sel(prev == 3, ab1, 0.f) + sel(cc2 == 3, ab2, 0.f);
            *reinterpret_cast<float4*>(&lds[l * ROWB + ti * 16]) = make_float4(l0, l1, l2, l3);
        }
        __syncthreads();
#pragma unroll
        for (int pp = 0; pp < 16; ++pp) {
            const int ss = pp * 4 + (l >> 4);
            const int st = l & 15;
            const float4 v = *reinterpret_cast<const float4*>(&lds[ss * ROWB + st * 16]);
            out4[((size_t)(blk * 64 + ss)) * T_ + k * CH + st] = v;
        }
        __syncthreads();
        cur = nxt;
    }
}

extern "C" void kernel_launch(void* const* d_in, const int* in_sizes, int n_in,
                              void* d_out, int out_size, void* d_ws, size_t ws_size,
                              hipStream_t stream) {
    const float* inputs = (const float*)d_in[0];   // [8192, 512, 8] f32
    const float* params = (const float*)d_in[1];   // [13] f32
    float* out = (float*)d_out;                    // [8192, 512, 4] f32

    if (ws_size >= PACK_BYTES + SNAP_BYTES) {
        unsigned char* pk = (unsigned char*)d_ws;
        float4* snap4 = (float4*)((char*)d_ws + PACK_BYTES);
        pack_kernel<<<dim3((B_ * T_) / 256), dim3(256), 0, stream>>>(inputs, pk);
        scan_snap<<<dim3(B_ / 8), dim3(256), 0, stream>>>(pk, params, snap4);
        chunk_logits<<<dim3(GRPS * NCH), dim3(64), 0, stream>>>(pk, params, snap4, out);
    } else if (ws_size >= PACK_BYTES) {
        unsigned char* pk = (unsigned char*)d_ws;
        pack_kernel<<<dim3((B_ * T_) / 256), dim3(256), 0, stream>>>(inputs, pk);
        castro_scan_packed<<<dim3(GRPS), dim3(64), 0, stream>>>(pk, params, out);
    }
}